// Round 3
// baseline (141.319 us; speedup 1.0000x reference)
//
#include <hip/hip_runtime.h>
#include <float.h>

// Problem constants (from reference setup_inputs)
#define NS   16384   // samples
#define K1   512     // d_in
#define F    256     // n_feat
#define NC   1000    // n_classes
#define SPB  64      // samples per block (halves means L2 traffic vs 32)
#define NTHR 512     // 8 waves
#define NBLK (NS / SPB)   // 256 blocks = exactly 1 per CU

// f16 split-precision MFMA plan:
//   value = hi + lo, hi = f16(v), lo = f16(v - hi)  => 2^-22 relative capture.
//   A*B ~= Ah*Bh + Ah*Bl + Al*Bh  (ll term ~2^-22 rel, dropped).
//   Pre-scale x*8, W*16, means*16: keeps lo terms in f16-normal range and is
//   argmax-invariant (positive scales).
// MFMA 16x16x32 f16 layouts (HW-verified m89/m91/m120):
//   A[m][k]: m=lane&15, k=(lane>>4)*8+j   (8 f16 per lane, k-contiguous)
//   B[k][n]: n=lane&15, k=(lane>>4)*8+j
//   C/D:     col=lane&15, row=(lane>>4)*4+reg
// Tie-break: reference argmin takes FIRST min => lowest class index wins.

typedef _Float16 half8  __attribute__((ext_vector_type(8)));
typedef _Float16 half4v __attribute__((ext_vector_type(4)));
typedef float    float4v __attribute__((ext_vector_type(4)));

// Workspace layout in halves (_Float16), TILE-INTERLEAVED hi/lo:
//   W region:  256 tiles (tile = ks*16+nt), each tile 1024 halves:
//              hi at tile*1024 + lane*8, lo at tile*1024 + 512 + lane*8
//   M region:  512 tiles (tile = ks*64+gt) at M_OFF, same intra-tile layout.
#define M_OFF 262144

#define PREP_BLKS 192
#define ZERO_BLKS 2048   // 2048 blk * 256 thr * 8 float4 = 67.1 MB >= 64 MB

// ---- merged prep: fragment swizzle (blocks 0..191) + output zeroing ----
// Zeroing lives HERE so fused_mfma has no bulk stores: vmcnt is in-order, so
// interleaved stores would couple phase-2 load waits to HBM write drain.
__global__ void prep(const float* __restrict__ W, const float* __restrict__ means,
                     _Float16* __restrict__ ws, float* __restrict__ out) {
    const int bid = blockIdx.x;
    if (bid >= PREP_BLKS) {
        // pure write blocks: zero the one-hot output (64 MB)
        const size_t total4 = (size_t)NS * NC / 4;     // 4,096,000 float4
        const float4v z4 = (float4v){0.f, 0.f, 0.f, 0.f};
        size_t base = (size_t)(bid - PREP_BLKS) * 2048 + threadIdx.x;
#pragma unroll
        for (int j = 0; j < 8; ++j) {
            size_t q = base + (size_t)j * 256;
            if (q < total4)
                __builtin_nontemporal_store(
                    z4, reinterpret_cast<float4v*>(out) + q);
        }
        return;
    }
    int g = bid * blockDim.x + threadIdx.x;            // 0..49151
    if (g < 16384) {
        int lane = g & 63, tile = g >> 6;              // tile = ks*16+nt
        int ks = tile >> 4, nt = tile & 15;
        int k0 = ks * 32 + (lane >> 4) * 8;
        int n  = nt * 16 + (lane & 15);
        half8 hv, lv;
#pragma unroll
        for (int j = 0; j < 8; ++j) {
            float v = W[(size_t)(k0 + j) * F + n] * 16.0f;
            _Float16 hi = (_Float16)v;
            hv[j] = hi;
            lv[j] = (_Float16)(v - (float)hi);
        }
        _Float16* d = ws + (size_t)tile * 1024 + (size_t)lane * 8;
        *reinterpret_cast<half8*>(d)       = hv;
        *reinterpret_cast<half8*>(d + 512) = lv;
    } else {
        int gm = g - 16384;                            // 0..32767
        int lane = gm & 63, tile = gm >> 6;            // tile = ks*64+gt
        int ks = tile >> 6, gt = tile & 63;
        int k0 = ks * 32 + (lane >> 4) * 8;
        int c  = gt * 16 + (lane & 15);
        half8 hv, lv;
#pragma unroll
        for (int j = 0; j < 8; ++j) {
            float v = (c < NC) ? means[(size_t)c * F + k0 + j] * 16.0f : 0.0f;
            _Float16 hi = (_Float16)v;
            hv[j] = hi;
            lv[j] = (_Float16)(v - (float)hi);
        }
        _Float16* d = ws + M_OFF + (size_t)tile * 1024 + (size_t)lane * 8;
        *reinterpret_cast<half8*>(d)       = hv;
        *reinterpret_cast<half8*>(d + 512) = lv;
    }
}

#define MFMA(a, b, c) __builtin_amdgcn_mfma_f32_16x16x32_f16((a), (b), (c), 0, 0, 0)

__attribute__((amdgpu_flat_work_group_size(NTHR, NTHR), amdgpu_waves_per_eu(2, 4)))
__global__ void fused_mfma(const float* __restrict__ x,
                           const _Float16* __restrict__ ws,
                           float* __restrict__ out) {
    // 1 block/CU, 8 waves (2/SIMD; register ceiling: 128 arch VGPR + 128
    // AGPR accumulator = 256/wave). Latency hiding is pure ILP: register
    // double-buffers on every global stream, no stores in the hot loops.
    __shared__ _Float16 xsh[2][64][40];   // x chunk hi, ping-pong, padded stride
    __shared__ _Float16 xsl[2][64][40];   // x chunk lo
    __shared__ _Float16 fh[64][264];      // feats hi (scaled x128), padded stride
    __shared__ _Float16 fl[64][264];      // feats lo
    __shared__ float cand_v[64][8];
    __shared__ int   cand_i[64][8];
    __shared__ int   bidx[64];

    const int tid  = threadIdx.x;
    const int lane = tid & 63;
    const int w    = tid >> 6;    // wave 0..7
    const int quad = lane >> 4;   // 0..3
    const int cl   = lane & 15;
    const int s0   = blockIdx.x * SPB;

    // staging coords: 512 threads cover 64 rows x 32 cols (float4 each)
    const int xrow = tid >> 3;          // 0..63
    const int xc4  = (tid & 7) * 4;     // 0,4,..,28

    // ================= Phase 1: feats = (8x) @ (16W), f16-split MFMA ========
    float4v acc1[2][4];   // [p = n-subtile][mt]
#pragma unroll
    for (int p = 0; p < 2; ++p)
#pragma unroll
        for (int mt = 0; mt < 4; ++mt)
            acc1[p][mt] = (float4v){0.f, 0.f, 0.f, 0.f};

    // W-fragment register double-buffer: prefetch ks+1 while MFMAing ks
    const _Float16* wsrc = ws + ((size_t)(w * 2) << 10) + ((size_t)lane << 3);
    half8 wbh[2][2], wbl[2][2];
#pragma unroll
    for (int p = 0; p < 2; ++p) {
        wbh[0][p] = *reinterpret_cast<const half8*>(wsrc + p * 1024);
        wbl[0][p] = *reinterpret_cast<const half8*>(wsrc + p * 1024 + 512);
    }

    float4v xv = __builtin_nontemporal_load(
        reinterpret_cast<const float4v*>(x + (size_t)(s0 + xrow) * K1 + xc4));

#pragma unroll
    for (int ks = 0; ks < 16; ++ks) {
        const int buf = ks & 1;
        {   // convert (scale x8) and stage as packed b64 writes
            half4v hx, lx;
#pragma unroll
            for (int j = 0; j < 4; ++j) {
                float v = xv[j] * 8.0f;
                _Float16 hi = (_Float16)v;
                hx[j] = hi;
                lx[j] = (_Float16)(v - (float)hi);
            }
            *reinterpret_cast<half4v*>(&xsh[buf][xrow][xc4]) = hx;
            *reinterpret_cast<half4v*>(&xsl[buf][xrow][xc4]) = lx;
        }
        __syncthreads();
        // x prefetch AFTER the barrier: the pre-barrier vmcnt(0) drain would
        // otherwise stall the whole block for the full ~900cy HBM latency of
        // a just-issued load. Issued here, it ages a full MFMA block (~930cy)
        // before the next barrier drains it.
        if (ks < 15)
            xv = __builtin_nontemporal_load(
                reinterpret_cast<const float4v*>(
                    x + (size_t)(s0 + xrow) * K1 + (ks + 1) * 32 + xc4));
        if (ks < 15) {   // prefetch next-ks W fragments across the MFMAs below
#pragma unroll
            for (int p = 0; p < 2; ++p) {
                wbh[buf ^ 1][p] = *reinterpret_cast<const half8*>(
                    wsrc + (size_t)(ks + 1) * 16384 + p * 1024);
                wbl[buf ^ 1][p] = *reinterpret_cast<const half8*>(
                    wsrc + (size_t)(ks + 1) * 16384 + p * 1024 + 512);
            }
        }
        half8 ah[4], al[4];
#pragma unroll
        for (int mt = 0; mt < 4; ++mt) {
            ah[mt] = *reinterpret_cast<const half8*>(&xsh[buf][mt * 16 + cl][quad * 8]);
            al[mt] = *reinterpret_cast<const half8*>(&xsl[buf][mt * 16 + cl][quad * 8]);
        }
#pragma unroll
        for (int p = 0; p < 2; ++p)
#pragma unroll
            for (int mt = 0; mt < 4; ++mt) {
                acc1[p][mt] = MFMA(ah[mt], wbh[buf][p], acc1[p][mt]);
                acc1[p][mt] = MFMA(ah[mt], wbl[buf][p], acc1[p][mt]);
                acc1[p][mt] = MFMA(al[mt], wbh[buf][p], acc1[p][mt]);
            }
        // no trailing barrier: next iter writes the other buffer
    }

    // park feats (scaled x128) into LDS as f16 hi/lo
#pragma unroll
    for (int p = 0; p < 2; ++p)
#pragma unroll
        for (int mt = 0; mt < 4; ++mt)
#pragma unroll
            for (int r = 0; r < 4; ++r) {
                int srow = mt * 16 + quad * 4 + r;
                int n    = (w * 2 + p) * 16 + cl;
                float v  = acc1[p][mt][r];
                _Float16 hi = (_Float16)v;
                fh[srow][n] = hi;
                fl[srow][n] = (_Float16)(v - (float)hi);
            }
    __syncthreads();

    // ========== Phase 2: scores = feats @ means.T, f16-split MFMA ==========
    // Wave w owns class tiles gt = w*8..w*8+7 (classes w*128..w*128+127) for
    // all 4 M-tiles => each B-frag load feeds 12 MFMAs. Register dbuf for
    // means fragments (prefetch tile ii+1 during tile ii's 12 MFMAs).
    // NO stores in this loop: load waits stay decoupled from write drain.
    float4v acc2[4][8];   // [mt][gt]
#pragma unroll
    for (int mt = 0; mt < 4; ++mt)
#pragma unroll
        for (int gt = 0; gt < 8; ++gt)
            acc2[mt][gt] = (float4v){0.f, 0.f, 0.f, 0.f};

    const _Float16* mbase = ws + M_OFF + ((size_t)(w * 8) << 10) + ((size_t)lane << 3);

    half8 mh[2], ml[2];
    mh[0] = *reinterpret_cast<const half8*>(mbase);
    ml[0] = *reinterpret_cast<const half8*>(mbase + 512);

#pragma unroll
    for (int ks = 0; ks < 8; ++ks) {
        half8 fah[4], fal[4];
#pragma unroll
        for (int mt = 0; mt < 4; ++mt) {
            fah[mt] = *reinterpret_cast<const half8*>(
                &fh[mt * 16 + cl][ks * 32 + quad * 8]);
            fal[mt] = *reinterpret_cast<const half8*>(
                &fl[mt * 16 + cl][ks * 32 + quad * 8]);
        }
#pragma unroll
        for (int gt = 0; gt < 8; ++gt) {
            const int ii = ks * 8 + gt;
            const int cb = ii & 1;
            if (ii < 63) {   // prefetch next means tile
                const _Float16* src = mbase +
                    (size_t)(((ii + 1) >> 3) * 65536 + ((ii + 1) & 7) * 1024);
                mh[cb ^ 1] = *reinterpret_cast<const half8*>(src);
                ml[cb ^ 1] = *reinterpret_cast<const half8*>(src + 512);
            }
#pragma unroll
            for (int mt = 0; mt < 4; ++mt) {
                acc2[mt][gt] = MFMA(fah[mt], mh[cb], acc2[mt][gt]);
                acc2[mt][gt] = MFMA(fah[mt], ml[cb], acc2[mt][gt]);
                acc2[mt][gt] = MFMA(fal[mt], mh[cb], acc2[mt][gt]);
            }
        }
    }

    // ---- argmax from C/D layout: row=quad*4+r, col=cl ----
#pragma unroll
    for (int mt = 0; mt < 4; ++mt)
#pragma unroll
        for (int r = 0; r < 4; ++r) {
            float v  = -FLT_MAX;
            int   ix = 0x7FFFFFFF;
#pragma unroll
            for (int nt = 0; nt < 8; ++nt) {          // ascending class order
                int c = (w * 8 + nt) * 16 + cl;
                if (c < NC) {
                    float sc = acc2[mt][nt][r];
                    if (sc > v) { v = sc; ix = c; }   // strict >: lowest wins
                }
            }
            // merge across the 16 lanes of this quad (they hold cl=0..15)
#pragma unroll
            for (int off = 1; off < 16; off <<= 1) {
                float ov = __shfl_xor(v, off, 64);
                int   oi = __shfl_xor(ix, off, 64);
                if (ov > v || (ov == v && oi < ix)) { v = ov; ix = oi; }
            }
            if (cl == 0) {
                int srow = mt * 16 + quad * 4 + r;
                cand_v[srow][w] = v;
                cand_i[srow][w] = ix;
            }
        }
    __syncthreads();

    if (tid < SPB) {   // merge the 8 wave-candidates, ascending class ranges
        float v  = cand_v[tid][0];
        int   ix = cand_i[tid][0];
#pragma unroll
        for (int q = 1; q < 8; ++q) {
            float ov = cand_v[tid][q];
            int   oi = cand_i[tid][q];
            if (ov > v || (ov == v && oi < ix)) { v = ov; ix = oi; }
        }
        bidx[tid] = ix;
    }
    __syncthreads();

    // ================= Epilogue: single 1.0 per row =================
    // (zeros were written by prep's zero-blocks; kernel boundary orders them)
    if (tid < SPB)
        out[(size_t)(s0 + tid) * NC + bidx[tid]] = 1.0f;
}

extern "C" void kernel_launch(void* const* d_in, const int* in_sizes, int n_in,
                              void* d_out, int out_size, void* d_ws, size_t ws_size,
                              hipStream_t stream) {
    const float* x     = (const float*)d_in[0];
    const float* W     = (const float*)d_in[1];
    const float* means = (const float*)d_in[2];
    float* out         = (float*)d_out;
    _Float16* ws       = (_Float16*)d_ws;   // 1.5 MB of swizzled f16 fragments

    prep<<<PREP_BLKS + ZERO_BLKS, 256, 0, stream>>>(W, means, ws, out);
    fused_mfma<<<NBLK, NTHR, 0, stream>>>(x, ws, out);
}

// Round 4
// 135.280 us; speedup vs baseline: 1.0446x; 1.0446x over previous
//
#include <hip/hip_runtime.h>
#include <float.h>

// Problem constants (from reference setup_inputs)
#define NS   16384   // samples
#define K1   512     // d_in
#define F    256     // n_feat
#define NC   1000    // n_classes
#define SPB  64      // samples per block
#define NTHR 512     // 8 waves
#define NBLK (NS / SPB)   // 256 blocks = 1 per CU

// f16 split-precision MFMA plan:
//   value = hi + lo, hi = f16(v), lo = f16(v - hi)  => 2^-22 relative capture.
//   A*B ~= Ah*Bh + Ah*Bl + Al*Bh  (ll term ~2^-22 rel, dropped).
//   Pre-scale x*8, W*16, means*16 (argmax-invariant positive scales).
// MFMA 16x16x32 f16 layouts (HW-verified m89/m91/m120):
//   A[m][k]: m=lane&15, k=(lane>>4)*8+j ; B[k][n]: n=lane&15, k=(lane>>4)*8+j
//   C/D: col=lane&15, row=(lane>>4)*4+reg
// Tie-break: reference argmin takes FIRST min => lowest class index wins.

typedef _Float16 half8  __attribute__((ext_vector_type(8)));
typedef _Float16 half4v __attribute__((ext_vector_type(4)));
typedef float    float4v __attribute__((ext_vector_type(4)));

// Workspace (halves), TILE-INTERLEAVED hi/lo:
//   W: 256 tiles (ks*16+nt) * 1024 halves (hi at +0, lo at +512)
//   M: 512 tiles (ks*64+gt) at M_OFF, same intra-tile layout
#define M_OFF 262144

#define PREP_BLKS 192
#define ZERO_BLKS 2048   // 2048 blk * 256 thr * 8 float4 = 67.1 MB >= 64 MB

// ---- merged prep: fragment swizzle + output zeroing (keeps fused store-free)
__global__ void prep(const float* __restrict__ W, const float* __restrict__ means,
                     _Float16* __restrict__ ws, float* __restrict__ out) {
    const int bid = blockIdx.x;
    if (bid >= PREP_BLKS) {
        const size_t total4 = (size_t)NS * NC / 4;
        const float4v z4 = (float4v){0.f, 0.f, 0.f, 0.f};
        size_t base = (size_t)(bid - PREP_BLKS) * 2048 + threadIdx.x;
#pragma unroll
        for (int j = 0; j < 8; ++j) {
            size_t q = base + (size_t)j * 256;
            if (q < total4)
                __builtin_nontemporal_store(z4, reinterpret_cast<float4v*>(out) + q);
        }
        return;
    }
    int g = bid * blockDim.x + threadIdx.x;            // 0..49151
    if (g < 16384) {
        int lane = g & 63, tile = g >> 6;              // tile = ks*16+nt
        int ks = tile >> 4, nt = tile & 15;
        int k0 = ks * 32 + (lane >> 4) * 8;
        int n  = nt * 16 + (lane & 15);
        half8 hv, lv;
#pragma unroll
        for (int j = 0; j < 8; ++j) {
            float v = W[(size_t)(k0 + j) * F + n] * 16.0f;
            _Float16 hi = (_Float16)v;
            hv[j] = hi;
            lv[j] = (_Float16)(v - (float)hi);
        }
        _Float16* d = ws + (size_t)tile * 1024 + (size_t)lane * 8;
        *reinterpret_cast<half8*>(d)       = hv;
        *reinterpret_cast<half8*>(d + 512) = lv;
    } else {
        int gm = g - 16384;                            // 0..32767
        int lane = gm & 63, tile = gm >> 6;            // tile = ks*64+gt
        int ks = tile >> 6, gt = tile & 63;
        int k0 = ks * 32 + (lane >> 4) * 8;
        int c  = gt * 16 + (lane & 15);
        half8 hv, lv;
#pragma unroll
        for (int j = 0; j < 8; ++j) {
            float v = (c < NC) ? means[(size_t)c * F + k0 + j] * 16.0f : 0.0f;
            _Float16 hi = (_Float16)v;
            hv[j] = hi;
            lv[j] = (_Float16)(v - (float)hi);
        }
        _Float16* d = ws + M_OFF + (size_t)tile * 1024 + (size_t)lane * 8;
        *reinterpret_cast<half8*>(d)       = hv;
        *reinterpret_cast<half8*>(d + 512) = lv;
    }
}

#define MFMA(a, b, c) __builtin_amdgcn_mfma_f32_16x16x32_f16((a), (b), (c), 0, 0, 0)

// Counted vmcnt wait (n is compile-time after unroll; switch folds to one case)
__device__ __forceinline__ void vmwait(int n) {
    switch (n) {
        case 0: asm volatile("s_waitcnt vmcnt(0)" ::: "memory"); break;
        case 2: asm volatile("s_waitcnt vmcnt(2)" ::: "memory"); break;
        case 4: asm volatile("s_waitcnt vmcnt(4)" ::: "memory"); break;
        default: asm volatile("s_waitcnt vmcnt(6)" ::: "memory"); break;
    }
    __builtin_amdgcn_sched_barrier(0);   // rule-18 fence: no hoist past the wait
}

// LDS layout in halves:
//   fh [64][264] at 0, fl at 16896  (feats hi/lo, padded stride)
//   OVL at 33792: phase1 xsh[2][64][40] (5120) + xsl (5120)
//                 phase2 per-wave means FIFO: w*4096, 4 slots * 1024 halves
#define FH_OFF  0
#define FL_OFF  16896
#define OVL_OFF 33792
#define SH_HALVES (33792 + 32768)

__attribute__((amdgpu_flat_work_group_size(NTHR, NTHR), amdgpu_waves_per_eu(2, 4)))
__global__ void fused_mfma(const float* __restrict__ x,
                           const _Float16* __restrict__ ws,
                           float* __restrict__ out) {
    __shared__ _Float16 SH[SH_HALVES];   // ~133 KB
    __shared__ float cand_v[64][8];
    __shared__ int   cand_i[64][8];
    __shared__ int   bidx[64];

    const int tid  = threadIdx.x;
    const int lane = tid & 63;
    const int w    = tid >> 6;    // wave 0..7
    const int quad = lane >> 4;   // 0..3
    const int cl   = lane & 15;
    const int s0   = blockIdx.x * SPB;

    // staging coords: 512 threads cover 64 rows x 32 cols (float4 each)
    const int xrow = tid >> 3;          // 0..63
    const int xc4  = (tid & 7) * 4;     // 0,4,..,28

#define XSH(b,r,c) SH[OVL_OFF + (b)*2560 + (r)*40 + (c)]
#define XSL(b,r,c) SH[OVL_OFF + 5120 + (b)*2560 + (r)*40 + (c)]
#define FH(r,c)    SH[FH_OFF + (r)*264 + (c)]
#define FL(r,c)    SH[FL_OFF + (r)*264 + (c)]

    // ================= Phase 1: feats = (8x) @ (16W), f16-split MFMA ========
    float4v acc1[2][4];   // [p = n-subtile][mt]
#pragma unroll
    for (int p = 0; p < 2; ++p)
#pragma unroll
        for (int mt = 0; mt < 4; ++mt)
            acc1[p][mt] = (float4v){0.f, 0.f, 0.f, 0.f};

    // W-fragment register double-buffer: prefetch ks+1 while MFMAing ks
    const _Float16* wsrc = ws + ((size_t)(w * 2) << 10) + ((size_t)lane << 3);
    half8 wbh[2][2], wbl[2][2];
#pragma unroll
    for (int p = 0; p < 2; ++p) {
        wbh[0][p] = *reinterpret_cast<const half8*>(wsrc + p * 1024);
        wbl[0][p] = *reinterpret_cast<const half8*>(wsrc + p * 1024 + 512);
    }

    // plain (cached) x loads: L3-resident on replays; NT forced HBM every time
    float4v xv = *reinterpret_cast<const float4v*>(x + (size_t)(s0 + xrow) * K1 + xc4);

#pragma unroll
    for (int ks = 0; ks < 16; ++ks) {
        const int buf = ks & 1;
        {   // convert (scale x8) and stage as packed b64 writes
            half4v hx, lx;
#pragma unroll
            for (int j = 0; j < 4; ++j) {
                float v = xv[j] * 8.0f;
                _Float16 hi = (_Float16)v;
                hx[j] = hi;
                lx[j] = (_Float16)(v - (float)hi);
            }
            *reinterpret_cast<half4v*>(&XSH(buf, xrow, xc4)) = hx;
            *reinterpret_cast<half4v*>(&XSL(buf, xrow, xc4)) = lx;
        }
        __syncthreads();
        if (ks < 15)
            xv = *reinterpret_cast<const float4v*>(
                x + (size_t)(s0 + xrow) * K1 + (ks + 1) * 32 + xc4);
        if (ks < 15) {   // prefetch next-ks W fragments across the MFMAs below
#pragma unroll
            for (int p = 0; p < 2; ++p) {
                wbh[buf ^ 1][p] = *reinterpret_cast<const half8*>(
                    wsrc + (size_t)(ks + 1) * 16384 + p * 1024);
                wbl[buf ^ 1][p] = *reinterpret_cast<const half8*>(
                    wsrc + (size_t)(ks + 1) * 16384 + p * 1024 + 512);
            }
        }
        half8 ah[4], al[4];
#pragma unroll
        for (int mt = 0; mt < 4; ++mt) {
            ah[mt] = *reinterpret_cast<const half8*>(&XSH(buf, mt * 16 + cl, quad * 8));
            al[mt] = *reinterpret_cast<const half8*>(&XSL(buf, mt * 16 + cl, quad * 8));
        }
#pragma unroll
        for (int p = 0; p < 2; ++p)
#pragma unroll
            for (int mt = 0; mt < 4; ++mt) {
                acc1[p][mt] = MFMA(ah[mt], wbh[buf][p], acc1[p][mt]);
                acc1[p][mt] = MFMA(ah[mt], wbl[buf][p], acc1[p][mt]);
                acc1[p][mt] = MFMA(al[mt], wbh[buf][p], acc1[p][mt]);
            }
        // no trailing barrier: next iter writes the other buffer
    }

    // park feats (scaled x128) into LDS as f16 hi/lo
#pragma unroll
    for (int p = 0; p < 2; ++p)
#pragma unroll
        for (int mt = 0; mt < 4; ++mt)
#pragma unroll
            for (int r = 0; r < 4; ++r) {
                int srow = mt * 16 + quad * 4 + r;
                int n    = (w * 2 + p) * 16 + cl;
                float v  = acc1[p][mt][r];
                _Float16 hi = (_Float16)v;
                FH(srow, n) = hi;
                FL(srow, n) = (_Float16)(v - (float)hi);
            }
    __syncthreads();   // all feats visible; also drains all phase-1 vmem

    // ========== Phase 2: scores = feats @ means.T, barrier-free pipeline ====
    // Wave w owns gt = c*8 + w for c = 0..7 within each ks (classes ascending
    // in c per wave; cross-wave merge is order-independent). Means tiles flow
    // through a PER-WAVE private LDS FIFO (4 slots x 2KB) fed by async
    // global_load_lds, staged 3 tiles ahead with counted vmcnt(4) waits —
    // never a full drain, never a barrier (no cross-wave LDS sharing).
    float4v acc2[4][8];   // [mt][c]
#pragma unroll
    for (int mt = 0; mt < 4; ++mt)
#pragma unroll
        for (int c = 0; c < 8; ++c)
            acc2[mt][c] = (float4v){0.f, 0.f, 0.f, 0.f};

    _Float16* fifo = &SH[OVL_OFF + w * 4096];
    const _Float16* mws = ws + M_OFF;

    // tile stream for wave w: T(i) at ((i>>3)*64 + (i&7)*8 + w)*1024 halves
#define MT_G(i) (mws + (size_t)((((i) >> 3) << 6) + (((i) & 7) << 3) + w) * 1024 \
                     + (size_t)lane * 8)
#define STAGE(i) do {                                                          \
        const _Float16* g_ = MT_G(i);                                          \
        _Float16* l_ = fifo + ((i) & 3) * 1024;                                \
        __builtin_amdgcn_global_load_lds(                                      \
            (const __attribute__((address_space(1))) void*)g_,                 \
            (__attribute__((address_space(3))) void*)l_, 16, 0, 0);            \
        __builtin_amdgcn_global_load_lds(                                      \
            (const __attribute__((address_space(1))) void*)(g_ + 512),         \
            (__attribute__((address_space(3))) void*)(l_ + 512), 16, 0, 0);    \
    } while (0)

    half8 fah[4], fal[4];
    half8 fbh[2], fbl[2];

    STAGE(0); STAGE(1); STAGE(2);           // 6 issues in flight
    vmwait(4);                              // T(0) landed
    fbh[0] = *reinterpret_cast<const half8*>(fifo + lane * 8);
    fbl[0] = *reinterpret_cast<const half8*>(fifo + 512 + lane * 8);

#pragma unroll
    for (int i = 0; i < 64; ++i) {
        if (i < 61) STAGE(i + 3);
        // outstanding after issue: T(i+1..i+3) = 6 -> vmcnt(4) retires T(i+1)
        if (i < 61)      vmwait(4);
        else if (i == 61) vmwait(2);        // retire T(62)
        else if (i == 62) vmwait(0);        // retire T(63)
        if (i < 63) {   // read-ahead next tile's fragments (slot i+1)
            const _Float16* sl = fifo + ((i + 1) & 3) * 1024 + lane * 8;
            fbh[(i + 1) & 1] = *reinterpret_cast<const half8*>(sl);
            fbl[(i + 1) & 1] = *reinterpret_cast<const half8*>(sl + 512);
        }
        if ((i & 7) == 0) {   // new ks: reload A-frags from feats LDS
            const int ks = i >> 3;
#pragma unroll
            for (int mt = 0; mt < 4; ++mt) {
                fah[mt] = *reinterpret_cast<const half8*>(
                    &FH(mt * 16 + cl, ks * 32 + quad * 8));
                fal[mt] = *reinterpret_cast<const half8*>(
                    &FL(mt * 16 + cl, ks * 32 + quad * 8));
            }
        }
        const int c = i & 7, rb = i & 1;
#pragma unroll
        for (int mt = 0; mt < 4; ++mt) {
            acc2[mt][c] = MFMA(fah[mt], fbh[rb], acc2[mt][c]);
            acc2[mt][c] = MFMA(fah[mt], fbl[rb], acc2[mt][c]);
            acc2[mt][c] = MFMA(fal[mt], fbh[rb], acc2[mt][c]);
        }
    }

    // ---- argmax from C/D layout: row=quad*4+r, col=cl ----
#pragma unroll
    for (int mt = 0; mt < 4; ++mt)
#pragma unroll
        for (int r = 0; r < 4; ++r) {
            float v  = -FLT_MAX;
            int   ix = 0x7FFFFFFF;
#pragma unroll
            for (int nt = 0; nt < 8; ++nt) {          // ascending class order
                int c = (nt * 8 + w) * 16 + cl;       // gt = nt*8 + w
                if (c < NC) {
                    float sc = acc2[mt][nt][r];
                    if (sc > v) { v = sc; ix = c; }   // strict >: lowest wins
                }
            }
#pragma unroll
            for (int off = 1; off < 16; off <<= 1) {  // merge quad's 16 lanes
                float ov = __shfl_xor(v, off, 64);
                int   oi = __shfl_xor(ix, off, 64);
                if (ov > v || (ov == v && oi < ix)) { v = ov; ix = oi; }
            }
            if (cl == 0) {
                int srow = mt * 16 + quad * 4 + r;
                cand_v[srow][w] = v;
                cand_i[srow][w] = ix;
            }
        }
    __syncthreads();

    if (tid < SPB) {   // merge the 8 wave-candidates (order-independent)
        float v  = cand_v[tid][0];
        int   ix = cand_i[tid][0];
#pragma unroll
        for (int q = 1; q < 8; ++q) {
            float ov = cand_v[tid][q];
            int   oi = cand_i[tid][q];
            if (ov > v || (ov == v && oi < ix)) { v = ov; ix = oi; }
        }
        bidx[tid] = ix;
    }
    __syncthreads();

    // ===== Epilogue: single 1.0 per row (zeros written by prep's blocks) ====
    if (tid < SPB)
        out[(size_t)(s0 + tid) * NC + bidx[tid]] = 1.0f;
}

extern "C" void kernel_launch(void* const* d_in, const int* in_sizes, int n_in,
                              void* d_out, int out_size, void* d_ws, size_t ws_size,
                              hipStream_t stream) {
    const float* x     = (const float*)d_in[0];
    const float* W     = (const float*)d_in[1];
    const float* means = (const float*)d_in[2];
    float* out         = (float*)d_out;
    _Float16* ws       = (_Float16*)d_ws;   // 1.5 MB of swizzled f16 fragments

    prep<<<PREP_BLKS + ZERO_BLKS, 256, 0, stream>>>(W, means, ws, out);
    fused_mfma<<<NBLK, NTHR, 0, stream>>>(x, ws, out);
}